// Round 13
// baseline (25.946 us; speedup 1.0000x reference)
//
#include <hip/hip_runtime.h>
#include <math.h>

#define BS    8192
#define NCTX  28
#define DM    28
#define QROW  36   // q row stride in floats: 144B, 16B-aligned

typedef __attribute__((ext_vector_type(8))) short    bfx8;
typedef __attribute__((ext_vector_type(16))) float   f32x16;

#define MFMA(A,B,C) __builtin_amdgcn_mfma_f32_32x32x16_bf16((A),(B),(C),0,0,0)

// split 8 floats into bf16-hi (truncate) + bf16-lo (residual)
__device__ __forceinline__ void cvt8(float4 a, float4 b, bfx8& hi, bfx8& lo) {
    float f[8] = {a.x,a.y,a.z,a.w,b.x,b.y,b.z,b.w};
    #pragma unroll
    for (int j = 0; j < 8; ++j) {
        unsigned xb = __float_as_uint(f[j]);
        unsigned hb = xb & 0xFFFF0000u;
        float    r  = f[j] - __uint_as_float(hb);
        hi[j] = (short)(hb >> 16);
        lo[j] = (short)(__float_as_uint(r) >> 16);
    }
}

// One wave = ONE item. lane = (p = channel class, r31 = token).
// D = W * x^T: C-layout row = (r&3)+8*(r>>2)+4*p = channel, col = r31 = token,
// so k/v land lane-local (no unpack). Class p owns channels with ((c>>2)&1)==p.
// Cross-class exchange via __shfl_xor(.,32) — compiler-visible, full-EXEC.
__global__ __launch_bounds__(256, 5) void l1att_fused(
    const float* __restrict__ x,
    const float* __restrict__ Wq, const float* __restrict__ bq,
    const float* __restrict__ Wk, const float* __restrict__ bk,
    const float* __restrict__ Wv, const float* __restrict__ bv,
    const float* __restrict__ W1, const float* __restrict__ b1,
    const float* __restrict__ W2, const float* __restrict__ b2,
    float* __restrict__ out)
{
    // W frags, bf16 hi/lo, exact A-fragment order: [op][slot][lane][8]
    __shared__ __align__(16) short wtab[3*4*64*8];       // 12288 B
    __shared__ __align__(16) float qsh[4][NCTX][QROW];   // 16128 B, f32 reg-order
    __shared__ float l1s[4][NCTX];
    __shared__ float hs [4][20];

    const int tid  = threadIdx.x;
    const int wv   = tid >> 6;          // wave = item slot (0..3)
    const int lw   = tid & 63;
    const int p    = lw >> 5;           // channel class
    const int r31  = lw & 31;           // token
    const int rc   = (r31 < 28) ? r31 : 27;
    const int item = blockIdx.x * 4 + wv;

    // ---- issue x loads FIRST (latency hides under table fill + barrier) ----
    const float* rowb = x + ((size_t)item * NCTX + rc) * DM;
    float4 xA0 = *(const float4*)(rowb + 8*p);
    float4 xA1 = *(const float4*)(rowb + 8*p + 4);
    float4 xB0 = *(const float4*)(rowb + 16 + 8*p);
    float4 xB1 = make_float4(1.f, 0.f, 0.f, 0.f);       // k=28 bias column = 1.0
    if (p == 0) xB1 = *(const float4*)(rowb + 20);

    // ---- cooperative W-fragment table fill (rows>=28 and k>28 -> 0) ----
    for (int u = tid; u < 384; u += 256) {
        int op = u >> 7, rem = u & 127, kt = rem >> 6, l = rem & 63;
        int pp = l >> 5, row = l & 31;
        const float* W  = (op==0) ? Wq : (op==1) ? Wk : Wv;
        const float* bb = (op==0) ? bq : (op==1) ? bk : bv;
        bfx8 hi, lo;
        #pragma unroll
        for (int j = 0; j < 8; ++j) {
            int k = 16*kt + 8*pp + j;
            float val = 0.f;
            if (row < 28) { if (k < 28) val = W[row*DM + k]; else if (k == 28) val = bb[row]; }
            unsigned hb = __float_as_uint(val) & 0xFFFF0000u;
            float    r  = val - __uint_as_float(hb);
            hi[j] = (short)(hb >> 16);
            lo[j] = (short)(__float_as_uint(r) >> 16);
        }
        *(bfx8*)&wtab[((op*4 + kt    )*64 + l)*8] = hi;   // slots 0,1: hi kt=0,1
        *(bfx8*)&wtab[((op*4 + 2 + kt)*64 + l)*8] = lo;   // slots 2,3: lo kt=0,1
    }
    __syncthreads();

    // ---- x B-fragments (split bf16): col=r31, k = 16*kt + 8*p + j ----
    bfx8 Xh0, Xl0, Xh1, Xl1;
    cvt8(xA0, xA1, Xh0, Xl0);
    cvt8(xB0, xB1, Xh1, Xl1);

#define RUN_OP(OP, D) do {                                                    \
        bfx8 Wh0 = *(const bfx8*)&wtab[(((OP)*4 + 0)*64 + lw)*8];             \
        bfx8 Wh1 = *(const bfx8*)&wtab[(((OP)*4 + 1)*64 + lw)*8];             \
        bfx8 Wl0 = *(const bfx8*)&wtab[(((OP)*4 + 2)*64 + lw)*8];             \
        bfx8 Wl1 = *(const bfx8*)&wtab[(((OP)*4 + 3)*64 + lw)*8];             \
        _Pragma("unroll")                                                     \
        for (int r_ = 0; r_ < 16; ++r_) D[r_] = 0.f;                          \
        D = MFMA(Wh0, Xh0, D);  D = MFMA(Wh1, Xh1, D);                        \
        D = MFMA(Wh0, Xl0, D);  D = MFMA(Wh1, Xl1, D);                        \
        D = MFMA(Wl0, Xh0, D);  D = MFMA(Wl1, Xh1, D);                        \
    } while (0)

    // ---- q: publish class-grouped f32 in REG ORDER (slot i <-> channel c(i)) ----
    {
        f32x16 qd;
        RUN_OP(0, qd);
        if (r31 < 28) {
            float4* qdst = (float4*)&qsh[wv][r31][p*16];
            qdst[0] = make_float4(qd[0], qd[1], qd[2], qd[3]);
            qdst[1] = make_float4(qd[4], qd[5], qd[6], qd[7]);
            qdst[2] = make_float4(qd[8], qd[9], qd[10], qd[11]);
            qdst[3] = make_float4(qd[12], qd[13], qd[14], qd[15]);
        }
    }

    // ---- k, v: stay in registers, class-split (16 f32 each) ----
    f32x16 kd, vd;
    RUN_OP(1, kd);
    RUN_OP(2, vd);

    // ---- L1 attention + row-dot with v (pure f32, FULL EXEC) ----
    {
        const float scale = -0.18898223650461363f;   // -1/sqrt(28)
        float sel0 = (p == 0) ? 1.f : 0.f;
        float sel1 = 1.f - sel0;
        float acc = 0.f;
        const float* qbase = &qsh[wv][0][p*16];
        #pragma unroll
        for (int j = 0; j < NCTX; ++j) {
            const float4* qp = (const float4*)(qbase + j*QROW);  // class-uniform bcast
            float4 a0 = qp[0], a1 = qp[1], a2 = qp[2], a3 = qp[3];
            float s0 = fabsf(a0.x - kd[0])  + fabsf(a1.x - kd[4]);
            float s1 = fabsf(a0.y - kd[1])  + fabsf(a1.y - kd[5]);
            float s2 = fabsf(a0.z - kd[2])  + fabsf(a1.z - kd[6]);
            float s3 = fabsf(a0.w - kd[3])  + fabsf(a1.w - kd[7]);
            s0 += fabsf(a2.x - kd[8])  + fabsf(a3.x - kd[12]);
            s1 += fabsf(a2.y - kd[9])  + fabsf(a3.y - kd[13]);
            s2 += fabsf(a2.z - kd[10]) + fabsf(a3.z - kd[14]);
            s3 += fabsf(a2.w - kd[11]) + fabsf(a3.w - kd[15]);
            float s = (s0 + s1) + (s2 + s3);             // own-class partial sum
            float full = s + __shfl_xor(s, 32, 64);      // class0 + class1
            float av = (j == r31) ? 1.0f : scale * full; // diagonal override
            float am = av * (((j >> 2) & 1) ? sel1 : sel0);  // owner class only
            acc = fmaf(am, vd[4*(j >> 3) + (j & 3)], acc);
        }
        float accT = __shfl_xor(acc, 32, 64);        // partial PV of other class
        if (p == 0 && r31 < 28) l1s[wv][r31] = acc + accT;
    }

    // ---- MLP (wave-private LDS deps, in-order DS pipe -> no barrier) ----
    if (p == 0 && r31 < 20) {
        float a = b1[r31];
        #pragma unroll
        for (int w = 0; w < NCTX; ++w) a += l1s[wv][w] * W1[r31*NCTX + w];
        hs[wv][r31] = fmaxf(a, 0.f);
    }
    if (p == 0 && r31 < 10) {
        float a = b2[r31];
        #pragma unroll
        for (int w = 0; w < 20; ++w) a += hs[wv][w] * W2[r31*20 + w];
        out[(size_t)item*10 + r31] = a;
    }
}

extern "C" void kernel_launch(void* const* d_in, const int* in_sizes, int n_in,
                              void* d_out, int out_size, void* d_ws, size_t ws_size,
                              hipStream_t stream) {
    const float* x  = (const float*)d_in[0];
    const float* Wq = (const float*)d_in[1];
    const float* bq = (const float*)d_in[2];
    const float* Wk = (const float*)d_in[3];
    const float* bk = (const float*)d_in[4];
    const float* Wv = (const float*)d_in[5];
    const float* bv = (const float*)d_in[6];
    const float* W1 = (const float*)d_in[7];
    const float* b1 = (const float*)d_in[8];
    const float* W2 = (const float*)d_in[9];
    const float* b2 = (const float*)d_in[10];
    float* out = (float*)d_out;

    dim3 grid(BS / 4), block(256);
    hipLaunchKernelGGL(l1att_fused, grid, block, 0, stream,
                       x, Wq, bq, Wk, bk, Wv, bv, W1, b1, W2, b2, out);
}